// Round 35
// baseline (200791.223 us; speedup 1.0000x reference)
//
#include <hip/hip_runtime.h>
#include <hip/hip_cooperative_groups.h>

constexpr int kNB = 64;    // batch
constexpr int kNS = 512;   // encoder sequence length
constexpr int kNH = 512;   // hidden dim
constexpr int kNG = 2048;  // 4*kNH gate rows
constexpr int kNT = 512;   // decoder steps

typedef _Float16 chpn_f16;

__device__ __forceinline__ float chpn_sigmoid(float x) {
    return 1.0f / (1.0f + __expf(-x));
}
__device__ __forceinline__ float chpn_tanh(float x) {
    x = fmaxf(fminf(x, 15.0f), -15.0f);
    float e = __expf(2.0f * x);
    return (e - 1.0f) / (e + 1.0f);
}

// group barrier: 4 blocks arrive; monotonic target (counters zeroed per call)
#define CHPN_BAR(barp, nbar)                                        \
    do {                                                            \
        __syncthreads();                                            \
        ++(nbar);                                                   \
        if (threadIdx.x == 0) {                                     \
            __threadfence();                                        \
            atomicAdd((barp), 1);                                   \
            while (atomicAdd((barp), 0) < 4 * (nbar)) {}            \
        }                                                           \
        __syncthreads();                                            \
        __threadfence();                                            \
    } while (0)

// ------- init: biases, transposed weights, zero state/counters -----------
__global__ void ConvexHullPointerNetwork_57303453663418_kernel(
    const float* ebih, const float* ebhh,
    const float* dbih, const float* dbhh,
    const float* ewhh, const float* dwih, const float* dwhh, const float* wq,
    float* enc_b, float* dec_b, float* weT, float* wdT, float* wqT,
    float* h_g, float* cfin, int* bars)
{
    size_t i = (size_t)blockIdx.x * 256 + threadIdx.x;
    size_t stride = (size_t)gridDim.x * 256;
    for (size_t x = i; x < (size_t)kNG; x += stride) {
        enc_b[x] = ebih[x] + ebhh[x];
        dec_b[x] = dbih[x] + dbhh[x];
    }
    for (size_t x = i; x < (size_t)kNH * kNG; x += stride) {    // weT[k][r]
        size_t k = x / kNG, r = x % kNG;
        weT[x] = ewhh[r * kNH + k];
    }
    for (size_t x = i; x < (size_t)2 * kNH * kNG; x += stride) { // wdT[k][r]
        size_t k = x / kNG, r = x % kNG;
        wdT[x] = (k < kNH) ? dwih[r * kNH + k] : dwhh[r * kNH + (k - kNH)];
    }
    for (size_t x = i; x < (size_t)kNH * kNH; x += stride) {    // wqT[j][h]
        size_t j = x / kNH, h = x % kNH;
        wqT[x] = wq[h * kNH + j];
    }
    for (size_t x = i; x < (size_t)2 * kNB * kNH; x += stride) h_g[x] = 0.0f;
    for (size_t x = i; x < (size_t)kNB * kNH; x += stride) cfin[x] = 0.0f;
    for (size_t x = i; x < 2048; x += stride) bars[x] = 0;
}

// ======= persistent encoder: 256 blocks x 1024 thr (group=batch) =========
__global__ __launch_bounds__(1024) void chpn_enc_p(
    const float* __restrict__ inputs, const float* __restrict__ wih,
    const float* __restrict__ weT, const float* __restrict__ bias,
    float* __restrict__ h_g, float* __restrict__ cfin,
    chpn_f16* __restrict__ enc_outs, int* __restrict__ bars)
{
    __shared__ float xl[kNH];
    __shared__ float gpart[2][512];
    __shared__ float gates[4][128];
    __shared__ float c_l[128];
    const int tid = threadIdx.x;
    const int g = (int)blockIdx.x >> 2, q = (int)blockIdx.x & 3;
    const int j0 = q * 128;
    const int row = tid & 511, kh = tid >> 9;
    const int seg = row >> 7, jj = row & 127;
    const int r = seg * kNH + j0 + jj;
    const float bias_r = bias[r];
    const float wx0 = wih[r * 2], wx1 = wih[r * 2 + 1];
    int* barp = bars + g * 16;
    int nbar = 0;
    if (tid < 128) c_l[tid] = 0.0f;

    for (int t = 0; t < kNS; ++t) {
        const int bufr = t & 1, bufw = bufr ^ 1;
        if (tid < kNH)
            xl[tid] = (t == 0) ? 0.0f : h_g[(size_t)bufr * kNB * kNH + g * kNH + tid];
        __syncthreads();
        float acc = 0.f;
        const float* wp = weT + (size_t)(kh * 256) * kNG + r;
        #pragma unroll 4
        for (int k = 0; k < 256; ++k)
            acc = fmaf(wp[(size_t)k * kNG], xl[kh * 256 + k], acc);
        gpart[kh][row] = acc;
        __syncthreads();
        if (tid < 512) {
            float x0 = inputs[(g * kNS + t) * 2 + 0];
            float x1 = inputs[(g * kNS + t) * 2 + 1];
            gates[seg][jj] = gpart[0][tid] + gpart[1][tid] + bias_r +
                             wx0 * x0 + wx1 * x1;
        }
        __syncthreads();
        if (tid < 128) {
            float gi = gates[0][tid], gf = gates[1][tid];
            float gc = gates[2][tid], go = gates[3][tid];
            float cc = chpn_sigmoid(gf) * c_l[tid] +
                       chpn_sigmoid(gi) * chpn_tanh(gc);
            float hh = chpn_sigmoid(go) * chpn_tanh(cc);
            c_l[tid] = cc;
            h_g[(size_t)bufw * kNB * kNH + g * kNH + j0 + tid] = hh;
            enc_outs[((size_t)g * kNS + t) * kNH + j0 + tid] = (chpn_f16)hh;
        }
        CHPN_BAR(barp, nbar);
    }
    if (tid < 128) cfin[g * kNH + j0 + tid] = c_l[tid];
}

// -------- keysT[b][h][s] GEMM (fp16 in/out) ------------------------------
__global__ __launch_bounds__(256) void chpn_keys_gemm(
    const chpn_f16* __restrict__ enc_outs, const float* __restrict__ wk,
    chpn_f16* __restrict__ keysT)
{
    int bid = blockIdx.x;
    int bb = bid >> 6, ht = (bid >> 3) & 7, st = bid & 7;
    __shared__ float asb[32][66];
    __shared__ float bsb[32][66];
    int tid = threadIdx.x;
    int tx = tid & 15, ty = tid >> 4;
    float acc[4][4] = {};
    for (int j0 = 0; j0 < kNH; j0 += 32) {
        for (int i = 0; i < 8; ++i) {
            int e = tid + i * 256;
            int j = e & 31, s = e >> 5;
            asb[j][s] = (float)enc_outs[((size_t)bb * kNS + st * 64 + s) * kNH + j0 + j];
            bsb[j][s] = wk[(size_t)(ht * 64 + s) * kNH + j0 + j];
        }
        __syncthreads();
        #pragma unroll 8
        for (int j = 0; j < 32; ++j) {
            float a0 = asb[j][tx*4], a1 = asb[j][tx*4+1], a2 = asb[j][tx*4+2], a3 = asb[j][tx*4+3];
            float b0 = bsb[j][ty*4], b1 = bsb[j][ty*4+1], b2 = bsb[j][ty*4+2], b3 = bsb[j][ty*4+3];
            acc[0][0] = fmaf(b0,a0,acc[0][0]); acc[0][1] = fmaf(b0,a1,acc[0][1]);
            acc[0][2] = fmaf(b0,a2,acc[0][2]); acc[0][3] = fmaf(b0,a3,acc[0][3]);
            acc[1][0] = fmaf(b1,a0,acc[1][0]); acc[1][1] = fmaf(b1,a1,acc[1][1]);
            acc[1][2] = fmaf(b1,a2,acc[1][2]); acc[1][3] = fmaf(b1,a3,acc[1][3]);
            acc[2][0] = fmaf(b2,a0,acc[2][0]); acc[2][1] = fmaf(b2,a1,acc[2][1]);
            acc[2][2] = fmaf(b2,a2,acc[2][2]); acc[2][3] = fmaf(b2,a3,acc[2][3]);
            acc[3][0] = fmaf(b3,a0,acc[3][0]); acc[3][1] = fmaf(b3,a1,acc[3][1]);
            acc[3][2] = fmaf(b3,a2,acc[3][2]); acc[3][3] = fmaf(b3,a3,acc[3][3]);
        }
        __syncthreads();
    }
    for (int i = 0; i < 4; ++i)
        for (int k = 0; k < 4; ++k)
            keysT[((size_t)bb * kNH + ht * 64 + ty * 4 + i) * kNS + st * 64 + tx * 4 + k] =
                (chpn_f16)acc[i][k];
}

// ======= persistent decoder: 256 blocks x 1024 thr (group=batch) =========
__global__ __launch_bounds__(1024) void chpn_dec_p(
    const float* __restrict__ wdT, const float* __restrict__ bias,
    const float* __restrict__ wqT, const float* __restrict__ vvec,
    const chpn_f16* __restrict__ keysT, const chpn_f16* __restrict__ enc_outs,
    float* __restrict__ h_g, const float* __restrict__ cfin,
    float* __restrict__ ctx_g, float* __restrict__ q_g,
    float* __restrict__ el_g, float* __restrict__ denomp,
    int* __restrict__ bars, float* __restrict__ out)
{
    __shared__ float xl[2 * kNH];
    __shared__ float gpart[2][512];
    __shared__ float gates[4][128];
    __shared__ float c_l[128];
    __shared__ float vl[kNH];
    __shared__ float buf8[8][128];
    __shared__ float dp2[2];
    __shared__ float dinv_l;
    const int tid = threadIdx.x;
    const int g = (int)blockIdx.x >> 2, q = (int)blockIdx.x & 3;
    const int j0 = q * 128;                 // j-range (CELL update, CTX)
    const int s0 = q * 128;                 // s-range (SCORE)
    const int h0q = q * 128;                // h-range (QUERY)
    const int row = tid & 511, kh = tid >> 9;
    const int seg = row >> 7, jj = row & 127;
    const int r = seg * kNH + j0 + jj;
    const float bias_r = bias[r];
    int* barp = bars + 1024 + g * 16;
    int nbar = 0;
    const chpn_f16* keyb = keysT + (size_t)g * kNH * kNS;
    const chpn_f16* encb2 = enc_outs + (size_t)g * kNS * kNH;

    if (tid < 128) c_l[tid] = cfin[g * kNH + j0 + tid];
    if (tid < kNH) vl[tid] = vvec[tid];

    for (int t = 0; t < kNT; ++t) {
        const int bufr = t & 1, bufw = bufr ^ 1;

        // ---- CELL ----------------------------------------------------
        if (tid < kNH)
            xl[tid] = (t == 0) ? 0.0f : ctx_g[g * kNH + tid];
        else
            xl[tid] = h_g[(size_t)bufr * kNB * kNH + g * kNH + (tid - kNH)];
        __syncthreads();
        float acc = 0.f;
        const float* wp = wdT + (size_t)(kh * 512) * kNG + r;
        #pragma unroll 4
        for (int k = 0; k < 512; ++k)
            acc = fmaf(wp[(size_t)k * kNG], xl[kh * 512 + k], acc);
        gpart[kh][row] = acc;
        __syncthreads();
        if (tid < 512) gates[seg][jj] = gpart[0][tid] + gpart[1][tid] + bias_r;
        __syncthreads();
        if (tid < 128) {
            float gi = gates[0][tid], gf = gates[1][tid];
            float gc = gates[2][tid], go = gates[3][tid];
            float cc = chpn_sigmoid(gf) * c_l[tid] +
                       chpn_sigmoid(gi) * chpn_tanh(gc);
            float hh = chpn_sigmoid(go) * chpn_tanh(cc);
            c_l[tid] = cc;
            h_g[(size_t)bufw * kNB * kNH + g * kNH + j0 + tid] = hh;
        }
        CHPN_BAR(barp, nbar);                       // B1: h published

        // ---- QUERY ---------------------------------------------------
        if (tid < kNH)
            xl[tid] = h_g[(size_t)bufw * kNB * kNH + g * kNH + tid];
        __syncthreads();
        {
            int hi = tid & 127, js = tid >> 7;
            float qa = 0.f;
            #pragma unroll 4
            for (int j = js * 64; j < js * 64 + 64; ++j)
                qa = fmaf(xl[j], wqT[(size_t)j * kNH + h0q + hi], qa);
            buf8[js][hi] = qa;
        }
        __syncthreads();
        if (tid < 128) {
            float qv = 0.f;
            #pragma unroll
            for (int o = 0; o < 8; ++o) qv += buf8[o][tid];
            q_g[g * kNH + h0q + tid] = qv;
        }
        CHPN_BAR(barp, nbar);                       // B2: q published

        // ---- SCORE ---------------------------------------------------
        if (tid < kNH) xl[tid] = q_g[g * kNH + tid];
        __syncthreads();
        {
            int si = tid & 127, hs = tid >> 7;
            float sa = 0.f;
            const chpn_f16* kp = keyb + s0 + si;
            #pragma unroll 4
            for (int h = hs * 64; h < hs * 64 + 64; ++h) {
                float kv = (float)kp[(size_t)h * kNS];
                sa = fmaf(vl[h], chpn_tanh(xl[h] + kv), sa);
            }
            buf8[hs][si] = sa;
        }
        __syncthreads();
        if (tid < 128) {
            float scv = 0.f;
            #pragma unroll
            for (int o = 0; o < 8; ++o) scv += buf8[o][tid];
            out[((size_t)g * kNT + t) * kNS + s0 + tid] = scv;
            float e = __expf(scv);                  // scores tiny; no max-sub
            el_g[g * kNH + s0 + tid] = e;
            float wsum = e;
            #pragma unroll
            for (int off = 32; off > 0; off >>= 1)
                wsum += __shfl_down(wsum, off);
            if ((tid & 63) == 0) dp2[tid >> 6] = wsum;
        }
        __syncthreads();
        if (tid == 0) denomp[g * 4 + q] = dp2[0] + dp2[1];
        CHPN_BAR(barp, nbar);                       // B3: el+denom published

        // ---- CTX -----------------------------------------------------
        if (tid < kNH) xl[tid] = el_g[g * kNH + tid];
        if (tid == 0) {
            float d = denomp[g * 4] + denomp[g * 4 + 1] +
                      denomp[g * 4 + 2] + denomp[g * 4 + 3];
            dinv_l = 1.0f / d;
        }
        __syncthreads();
        {
            int ji = tid & 127, ss = tid >> 7;
            float ca = 0.f;
            const chpn_f16* ep = encb2 + (size_t)(ss * 64) * kNH + j0 + ji;
            #pragma unroll 4
            for (int sx = 0; sx < 64; ++sx)
                ca = fmaf(xl[ss * 64 + sx], (float)ep[(size_t)sx * kNH], ca);
            buf8[ss][ji] = ca;
        }
        __syncthreads();
        if (tid < 128) {
            float cv = 0.f;
            #pragma unroll
            for (int o = 0; o < 8; ++o) cv += buf8[o][tid];
            ctx_g[g * kNH + j0 + tid] = cv * dinv_l;
        }
        if (t < kNT - 1) CHPN_BAR(barp, nbar);      // B4: ctx published
    }
}

// ======= fallback per-step kernels (R34, proven) =========================
__global__ __launch_bounds__(256) void fb_enc_cell(
    const float* __restrict__ inputs, const float* __restrict__ wih,
    const float* __restrict__ whh, const float* __restrict__ bias,
    const float* __restrict__ h_src, float* __restrict__ h_dst,
    float* __restrict__ c_st, chpn_f16* __restrict__ enc_outs, int t)
{
    __shared__ float tile[64][65];
    __shared__ float gate_lds[4][64];
    const int tid = threadIdx.x;
    const int bb = tid & 63, gg = tid >> 6;
    const int j = (int)blockIdx.x;
    const int r = gg * kNH + j;
    const float* w = whh + (size_t)r * kNH;
    float acc = 0.f;
    for (int ch = 0; ch < 8; ++ch) {
        const int k0 = ch * 64;
        for (int i = 0; i < 16; ++i) {
            int e = tid + i * 256; int kk = e & 63, b2 = e >> 6;
            tile[kk][b2] = h_src[b2 * kNH + k0 + kk];
        }
        __syncthreads();
        #pragma unroll
        for (int kk = 0; kk < 64; ++kk)
            acc = fmaf(tile[kk][bb], w[k0 + kk], acc);
        __syncthreads();
    }
    float x0 = inputs[(bb * kNS + t) * 2 + 0];
    float x1 = inputs[(bb * kNS + t) * 2 + 1];
    acc += bias[r] + wih[r * 2] * x0 + wih[r * 2 + 1] * x1;
    gate_lds[gg][bb] = acc;
    __syncthreads();
    if (tid < 64) {
        float gi = gate_lds[0][tid], gf = gate_lds[1][tid];
        float gc = gate_lds[2][tid], go = gate_lds[3][tid];
        float cc = chpn_sigmoid(gf) * c_st[tid * kNH + j] + chpn_sigmoid(gi) * chpn_tanh(gc);
        float hh = chpn_sigmoid(go) * chpn_tanh(cc);
        c_st[tid * kNH + j] = cc;
        h_dst[tid * kNH + j] = hh;
        enc_outs[((size_t)tid * kNS + t) * kNH + j] = (chpn_f16)hh;
    }
}

__global__ __launch_bounds__(256) void fb_dec_cell(
    const float* __restrict__ wih, const float* __restrict__ whh,
    const float* __restrict__ bias,
    const float* __restrict__ h_src, float* __restrict__ h_dst,
    float* __restrict__ c_st,
    const float* __restrict__ ctx_num, const float* __restrict__ denom,
    int first)
{
    __shared__ float tile[64][65];
    __shared__ float gate_lds[4][64];
    __shared__ float invd[64];
    const int tid = threadIdx.x;
    const int bb = tid & 63, gg = tid >> 6;
    const int j = (int)blockIdx.x;
    if (tid < 64) invd[tid] = first ? 0.0f : (1.0f / denom[tid]);
    __syncthreads();
    const int r = gg * kNH + j;
    float acc = 0.f;
    {
        const float* w = wih + (size_t)r * kNH;
        for (int ch = 0; ch < 8; ++ch) {
            const int k0 = ch * 64;
            for (int i = 0; i < 16; ++i) {
                int e = tid + i * 256; int kk = e & 63, b2 = e >> 6;
                tile[kk][b2] = first ? 0.0f : ctx_num[b2 * kNH + k0 + kk] * invd[b2];
            }
            __syncthreads();
            #pragma unroll
            for (int kk = 0; kk < 64; ++kk)
                acc = fmaf(tile[kk][bb], w[k0 + kk], acc);
            __syncthreads();
        }
    }
    {
        const float* w = whh + (size_t)r * kNH;
        for (int ch = 0; ch < 8; ++ch) {
            const int k0 = ch * 64;
            for (int i = 0; i < 16; ++i) {
                int e = tid + i * 256; int kk = e & 63, b2 = e >> 6;
                tile[kk][b2] = h_src[b2 * kNH + k0 + kk];
            }
            __syncthreads();
            #pragma unroll
            for (int kk = 0; kk < 64; ++kk)
                acc = fmaf(tile[kk][bb], w[k0 + kk], acc);
            __syncthreads();
        }
    }
    acc += bias[r];
    gate_lds[gg][bb] = acc;
    __syncthreads();
    if (tid < 64) {
        float gi = gate_lds[0][tid], gf = gate_lds[1][tid];
        float gc = gate_lds[2][tid], go = gate_lds[3][tid];
        float cc = chpn_sigmoid(gf) * c_st[tid * kNH + j] + chpn_sigmoid(gi) * chpn_tanh(gc);
        float hh = chpn_sigmoid(go) * chpn_tanh(cc);
        c_st[tid * kNH + j] = cc;
        h_dst[tid * kNH + j] = hh;
    }
}

__global__ __launch_bounds__(256) void fb_query(
    const float* __restrict__ wq, const float* __restrict__ h_src,
    float* __restrict__ query, float* __restrict__ ctx_num,
    float* __restrict__ denom)
{
    __shared__ float tile[128][65];
    __shared__ float qp[4][2][64];
    const int tid = threadIdx.x;
    const int bb = tid & 63, p = tid >> 6;
    const int h0 = (int)blockIdx.x * 2;
    const float* w0 = wq + (size_t)h0 * kNH;
    const float* w1 = w0 + kNH;
    float a0 = 0.f, a1 = 0.f;
    for (int ch = 0; ch < 4; ++ch) {
        const int j0 = ch * 128;
        for (int i = 0; i < 32; ++i) {
            int e = tid + i * 256; int jj = e & 127, b2 = e >> 7;
            tile[jj][b2] = h_src[b2 * kNH + j0 + jj];
        }
        __syncthreads();
        if (ch == p) {
            #pragma unroll 4
            for (int jj = 0; jj < 128; ++jj) {
                float hv = tile[jj][bb];
                a0 = fmaf(hv, w0[j0 + jj], a0);
                a1 = fmaf(hv, w1[j0 + jj], a1);
            }
        }
        __syncthreads();
    }
    qp[p][0][bb] = a0;
    qp[p][1][bb] = a1;
    __syncthreads();
    if (tid < 128) {
        int b2 = tid & 63, hh = tid >> 6;
        float qv = qp[0][hh][b2] + qp[1][hh][b2] + qp[2][hh][b2] + qp[3][hh][b2];
        query[b2 * kNH + h0 + hh] = qv;
        ctx_num[b2 * kNH + h0 + hh] = 0.0f;
        if (blockIdx.x == 0 && hh == 0) denom[b2] = 0.0f;
    }
}

__global__ __launch_bounds__(1024) void fb_score_ctx(
    const chpn_f16* __restrict__ keysT, const chpn_f16* __restrict__ enc_outs,
    const float* __restrict__ query, const float* __restrict__ vvec,
    float* __restrict__ ctx_num, float* __restrict__ denom,
    float* __restrict__ out, int t)
{
    __shared__ float ql[kNH], vl[kNH];
    __shared__ float part[16][64];
    __shared__ float el[64];
    int bid = blockIdx.x;
    int bb = bid >> 3, sc = bid & 7;
    int s0 = sc * 64;
    int tid = threadIdx.x;
    int s = tid & 63, hq = tid >> 6;
    if (tid < kNH) { ql[tid] = query[bb * kNH + tid]; vl[tid] = vvec[tid]; }
    __syncthreads();
    float acc = 0.f;
    const chpn_f16* kp = keysT + (size_t)bb * kNH * kNS + s0 + s;
    const int h0 = hq * 32;
    #pragma unroll 4
    for (int h = h0; h < h0 + 32; ++h) {
        float kv = (float)kp[(size_t)h * kNS];
        acc = fmaf(vl[h], chpn_tanh(ql[h] + kv), acc);
    }
    part[hq][s] = acc;
    __syncthreads();
    if (tid < 64) {
        float scv = 0.f;
        #pragma unroll
        for (int qq = 0; qq < 16; ++qq) scv += part[qq][tid];
        out[((size_t)bb * kNT + t) * kNS + s0 + tid] = scv;
        float e = __expf(scv);
        el[tid] = e;
        float wsum = e;
        #pragma unroll
        for (int off = 32; off > 0; off >>= 1) wsum += __shfl_down(wsum, off);
        if (tid == 0) atomicAdd(&denom[bb], wsum);
    }
    __syncthreads();
    int j = tid & 511, sh = tid >> 9;
    float a = 0.f;
    const chpn_f16* ep = enc_outs + ((size_t)bb * kNS + s0 + sh * 32) * kNH + j;
    #pragma unroll 4
    for (int ss = 0; ss < 32; ++ss)
        a = fmaf(el[sh * 32 + ss], (float)ep[(size_t)ss * kNH], a);
    atomicAdd(&ctx_num[bb * kNH + j], a);
}

extern "C" void kernel_launch(void* const* d_in, const int* in_sizes, int n_in,
                              void* d_out, int out_size, void* d_ws, size_t ws_size,
                              hipStream_t stream) {
    const float* inputs = (const float*)d_in[0];
    const float* e_wih  = (const float*)d_in[1];
    const float* e_whh  = (const float*)d_in[2];
    const float* e_bih  = (const float*)d_in[3];
    const float* e_bhh  = (const float*)d_in[4];
    const float* d_wih  = (const float*)d_in[5];
    const float* d_whh  = (const float*)d_in[6];
    const float* d_bih  = (const float*)d_in[7];
    const float* d_bhh  = (const float*)d_in[8];
    const float* w_key  = (const float*)d_in[9];
    const float* w_qry  = (const float*)d_in[10];
    const float* v_vec  = (const float*)d_in[11];
    float* out = (float*)d_out;               // f32 output (64 MB)

    float* wsf   = (float*)d_ws;
    float* encb  = wsf;                                     // 2048
    float* decb  = encb + kNG;                              // 2048
    float* wqT   = decb + kNG;                              // 262144
    float* weT   = wqT + (size_t)kNH * kNH;                 // 1048576
    float* wdT   = weT + (size_t)kNH * kNG;                 // 2097152
    float* h_g   = wdT + (size_t)2 * kNH * kNG;             // 2*kNB*kNH
    float* cfin  = h_g + (size_t)2 * kNB * kNH;             // kNB*kNH
    float* ctx_g = cfin + (size_t)kNB * kNH;                // kNB*kNH
    float* q_g   = ctx_g + (size_t)kNB * kNH;               // kNB*kNH
    float* el_g  = q_g + (size_t)kNB * kNH;                 // kNB*kNH
    float* denomp = el_g + (size_t)kNB * kNH;               // 256
    int*   bars  = (int*)(denomp + 256);                    // 2048 ints
    chpn_f16* keysH = (chpn_f16*)(bars + 2048);             // 33.5 MB
    chpn_f16* encH  = keysH + (size_t)kNB * kNH * kNS;      // 33.5 MB

    ConvexHullPointerNetwork_57303453663418_kernel<<<4096, 256, 0, stream>>>(
        e_bih, e_bhh, d_bih, d_bhh, e_whh, d_wih, d_whh, w_qry,
        encb, decb, weT, wdT, wqT, h_g, cfin, bars);

    float* h0 = h_g;                     // buf0
    float* h1 = h_g + (size_t)kNB * kNH; // buf1

    {   // persistent encoder (cooperative; fallback per-step)
        const float* a0 = inputs; const float* a1 = e_wih;
        const float* a2 = weT; const float* a3 = encb;
        float* a4 = h_g; float* a5 = cfin;
        chpn_f16* a6 = encH; int* a7 = bars;
        void* args[] = { &a0, &a1, &a2, &a3, &a4, &a5, &a6, &a7 };
        hipError_t rc = hipLaunchCooperativeKernel((const void*)chpn_enc_p,
                                                   dim3(256), dim3(1024),
                                                   args, 0, stream);
        if (rc != hipSuccess) {
            (void)hipGetLastError();
            for (int t = 0; t < kNS; ++t) {
                float* hs = (t & 1) ? h1 : h0;
                float* hd = (t & 1) ? h0 : h1;
                fb_enc_cell<<<512, 256, 0, stream>>>(inputs, e_wih, e_whh, encb,
                                                     hs, hd, cfin, encH, t);
            }
        }
    }

    chpn_keys_gemm<<<4096, 256, 0, stream>>>(encH, w_key, keysH);

    {   // persistent decoder (cooperative; fallback per-step)
        const float* a0 = wdT; const float* a1 = decb;
        const float* a2 = wqT; const float* a3 = v_vec;
        const chpn_f16* a4 = keysH; const chpn_f16* a5 = encH;
        float* a6 = h_g; const float* a7 = cfin;
        float* a8 = ctx_g; float* a9 = q_g; float* a10 = el_g;
        float* a11 = denomp; int* a12 = bars; float* a13 = out;
        void* args[] = { &a0, &a1, &a2, &a3, &a4, &a5, &a6, &a7,
                         &a8, &a9, &a10, &a11, &a12, &a13 };
        hipError_t rc = hipLaunchCooperativeKernel((const void*)chpn_dec_p,
                                                   dim3(256), dim3(1024),
                                                   args, 0, stream);
        if (rc != hipSuccess) {
            (void)hipGetLastError();
            for (int t = 0; t < kNT; ++t) {
                float* hs = (t & 1) ? h1 : h0;   // enc final h in buf0
                float* hd = (t & 1) ? h0 : h1;
                fb_dec_cell<<<512, 256, 0, stream>>>(d_wih, d_whh, decb,
                                                     hs, hd, cfin,
                                                     ctx_g, denomp, t == 0 ? 1 : 0);
                fb_query<<<256, 256, 0, stream>>>(w_qry, hd, q_g, ctx_g, denomp);
                fb_score_ctx<<<512, 1024, 0, stream>>>(keysH, encH, q_g, v_vec,
                                                       ctx_g, denomp, out, t);
            }
        }
    }
}